// Round 10
// baseline (5751.552 us; speedup 1.0000x reference)
//
#include <hip/hip_runtime.h>
#include <hip/hip_bf16.h>

constexpr int kB = 32;
constexpr int kN = 256;
constexpr int kR = 2048;
constexpr int kD = 1024;

typedef short bf16x8 __attribute__((ext_vector_type(8)));
typedef float f32x4 __attribute__((ext_vector_type(4)));
typedef unsigned short u16x8 __attribute__((ext_vector_type(8)));

__device__ __forceinline__ unsigned short f2bf(float f) {
  union { __hip_bfloat16 h; unsigned short u; } cv;
  cv.h = __float2bfloat16(f);
  return cv.u;
}

__device__ __forceinline__ void gload_lds16(const void* g, void* l) {
  __builtin_amdgcn_global_load_lds(
      (const __attribute__((address_space(1))) unsigned int*)g,
      (__attribute__((address_space(3))) unsigned int*)l, 16, 0, 0);
}

#define FENCE asm volatile("" ::: "memory")
#define LGKM0 asm volatile("s_waitcnt lgkmcnt(0)" ::: "memory")
#define WAITV(n) asm volatile("s_waitcnt vmcnt(" #n ")" ::: "memory")

// ---------------------------------------------------------------------------
// Fused f32->bf16 pre-pass for all 5 GEMM operands + out0 passthrough copy.
// ---------------------------------------------------------------------------
__global__ void cvt_all(const float* __restrict__ obj,
                        const float* __restrict__ attr,
                        const float* __restrict__ rela,
                        const float* __restrict__ wa,
                        const float* __restrict__ wr,
                        unsigned short* __restrict__ objb,
                        unsigned short* __restrict__ attrb,
                        unsigned short* __restrict__ relab,
                        unsigned short* __restrict__ wab,
                        unsigned short* __restrict__ wrb,
                        float* __restrict__ out0) {
  constexpr long n0 = (long)kB * kN * kD / 8;          // obj
  constexpr long c0 = n0;
  constexpr long c1 = c0 + n0;                          // attr
  constexpr long c2 = c1 + (long)kB * kR * kD / 8;      // rela
  constexpr long c3 = c2 + (long)kD * 2 * kD / 8;       // W_attr
  constexpr long c4 = c3 + (long)kD * 3 * kD / 8;       // W_rela
  const long stride = (long)gridDim.x * blockDim.x;
  for (long i = (long)blockIdx.x * blockDim.x + threadIdx.x; i < c4;
       i += stride) {
    const float* s;
    unsigned short* d;
    long j;
    bool isobj = false;
    if (i < c0)      { s = obj;  d = objb;  j = i; isobj = true; }
    else if (i < c1) { s = attr; d = attrb; j = i - c0; }
    else if (i < c2) { s = rela; d = relab; j = i - c1; }
    else if (i < c3) { s = wa;   d = wab;   j = i - c2; }
    else             { s = wr;   d = wrb;   j = i - c3; }
    const float4 a = reinterpret_cast<const float4*>(s)[2 * j];
    const float4 b = reinterpret_cast<const float4*>(s)[2 * j + 1];
    if (isobj) {  // out0 = obj passthrough, fused with the convert read
      reinterpret_cast<float4*>(out0)[2 * j] = a;
      reinterpret_cast<float4*>(out0)[2 * j + 1] = b;
    }
    u16x8 v;
    v[0] = f2bf(a.x); v[1] = f2bf(a.y); v[2] = f2bf(a.z); v[3] = f2bf(a.w);
    v[4] = f2bf(b.x); v[5] = f2bf(b.y); v[6] = f2bf(b.z); v[7] = f2bf(b.w);
    reinterpret_cast<u16x8*>(d)[j] = v;
  }
}

// ---------------------------------------------------------------------------
// 256x256 bf16 GEMM body, BK=32, 2-slot LDS ring (64 KB -> 2 BLOCKS/CU),
// one barrier + one counted vmcnt per tile. Cross-block TLP supplies the
// MFMA/LDS pipe overlap that intra-block schedules (R5/R7/R8, all ~44%
// MfmaUtil at 1 block/CU) could not: while one block sits in its
// barrier/wait segment, the co-resident block's waves issue MFMA (m114).
// Per tile t (slot S = t&1):
//   lgkm0+barrier   [all waves' reads of slot S^1 retired -> WAR safe]
//   issue(t+1 -> S^1)  [4 x gload_lds rounds: 2 A + 2 B]
//   WAITV(4)        [retires tile t's 4 rounds; t+1's stay in flight]
//   compute(t from S)  [12 ds_read_b128 + 32 MFMA, setprio-wrapped]
// Staging/read/swizzle geometry bit-identical to rounds 4-8 (0 conflicts).
// C[m,d] = relu(sum_k A[m,k]*W[d,k] + bias[d]) + resid[m,d]  (*mask[m] rela)
// A row = concat of 1024-wide segments (32 BK-tiles each):
//   attr: [objb m, attrb m]                      (K=2048, T=64)
//   rela: [objb[subj], relab m, objb[obji]]      (K=3072, T=96)
// ---------------------------------------------------------------------------
template <bool IS_RELA, int K_TOT, int LOG_RPB, int NPANEL>
__device__ __forceinline__ void gemm_body(
    int bid, unsigned short* smem,
    const unsigned short* __restrict__ objb,
    const unsigned short* __restrict__ seg1b,
    const unsigned short* __restrict__ Wb,
    const int* __restrict__ edges, const float* __restrict__ masks,
    const float* __restrict__ resid, const float* __restrict__ bias,
    float* __restrict__ out) {
  constexpr int T = K_TOT / 32;

  // XCD mapping: XCD x owns col panel (x>>1); (x&1) splits row panels.
  // Co-resident blocks on a CU share the same B col-panel -> L2-friendly.
  const int x = bid & 7;
  const int col0 = (x >> 1) * 256;
  const int panel = (x & 1) * (NPANEL / 2) + (bid >> 3);
  const int row0 = panel * 256;

  const int tid = threadIdx.x;
  const int w = tid >> 6;   // wave 0..7
  const int l = tid & 63;

  // staging: round r in {0,1} covers LDS rows (w*32 + r*16 + l>>2), granule
  // l&3 (16B); source pre-swizzle g = (l&3) ^ ((l>>3)&3) (rule #21).
  const int sw = (((l & 3) ^ ((l >> 3) & 3)) << 4);  // bytes
  const char* pA0[2];
  const char* pA1[2];
  const char* pA2[2];
  const char* pB[2];
#pragma unroll
  for (int r = 0; r < 2; ++r) {
    const int rl = w * 32 + r * 16 + (l >> 2);
    const int m = row0 + rl;
    if constexpr (IS_RELA) {
      const int b = m >> LOG_RPB;
      const int ri = m & ((1 << LOG_RPB) - 1);
      const int2 e =
          *reinterpret_cast<const int2*>(&edges[((size_t)b * kR + ri) * 2]);
      pA0[r] = (const char*)(objb + (size_t)(b * kN + e.x) * kD);
      pA1[r] = (const char*)(seg1b + (size_t)m * kD);
      pA2[r] = (const char*)(objb + (size_t)(b * kN + e.y) * kD);
    } else {
      pA0[r] = (const char*)(objb + (size_t)m * kD);
      pA1[r] = (const char*)(seg1b + (size_t)m * kD);
      pA2[r] = pA0[r];
    }
    pB[r] = (const char*)(Wb + (size_t)(col0 + rl) * K_TOT);
  }

  const int wr = w >> 2;
  const int wc = w & 3;
  const int lrow = l & 15;
  const int lgrp = l >> 4;
  const int pgr = ((lgrp ^ ((lrow >> 1) & 3)) << 3);  // shorts

  f32x4 acc[8][4] = {};

  auto issue = [&](int tn, int slot) {
    unsigned short* ra = smem + slot * 16384;
    unsigned short* rb = ra + 8192;
    const int seg = tn >> 5;                // wave-uniform
    const uint32_t ko = (uint32_t)(tn & 31) << 6;  // bytes in segment row
    const uint32_t kb = (uint32_t)tn << 6;         // bytes in W row
#pragma unroll
    for (int r = 0; r < 2; ++r) {
      const char* srcA;
      if constexpr (IS_RELA) {
        srcA = (seg == 1) ? pA1[r] : ((seg == 0) ? pA0[r] : pA2[r]);
      } else {
        srcA = (seg == 0) ? pA0[r] : pA1[r];
      }
      gload_lds16(srcA + ko + sw, ra + (w * 2 + r) * 512);
      gload_lds16(pB[r] + kb + sw, rb + (w * 2 + r) * 512);
    }
  };

  auto compute = [&](int slot) {
    const unsigned short* da = smem + slot * 16384;
    const unsigned short* db = da + 8192;
    bf16x8 bf[4], af[8];
#pragma unroll
    for (int ni = 0; ni < 4; ++ni)
      bf[ni] = *reinterpret_cast<const bf16x8*>(
          &db[(wc * 64 + ni * 16 + lrow) * 32 + pgr]);
#pragma unroll
    for (int mi = 0; mi < 8; ++mi)
      af[mi] = *reinterpret_cast<const bf16x8*>(
          &da[(wr * 128 + mi * 16 + lrow) * 32 + pgr]);
    __builtin_amdgcn_s_setprio(1);
#pragma unroll
    for (int mi = 0; mi < 8; ++mi)
#pragma unroll
      for (int ni = 0; ni < 4; ++ni)
        acc[mi][ni] = __builtin_amdgcn_mfma_f32_16x16x32_bf16(
            af[mi], bf[ni], acc[mi][ni], 0, 0, 0);
    __builtin_amdgcn_s_setprio(0);
  };

  // prologue: tile 0 in flight
  issue(0, 0);

  // main loop: tiles 0 .. T-3, unrolled by 2 (T even)
#pragma unroll 1
  for (int it = 0; it < (T - 2) / 2; ++it) {
    const int t = 2 * it;
    LGKM0; __builtin_amdgcn_s_barrier(); FENCE;
    issue(t + 1, 1);
    WAITV(4);
    compute(0);
    LGKM0; __builtin_amdgcn_s_barrier(); FENCE;
    issue(t + 2, 0);
    WAITV(4);
    compute(1);
  }
  // tail: tiles T-2, T-1
  LGKM0; __builtin_amdgcn_s_barrier(); FENCE;
  issue(T - 1, 1);
  WAITV(4);
  compute(0);
  LGKM0; __builtin_amdgcn_s_barrier(); FENCE;
  WAITV(0);
  compute(1);

  // epilogue: bias + relu + residual (+mask)
  float biasv[4];
#pragma unroll
  for (int ni = 0; ni < 4; ++ni)
    biasv[ni] = bias[col0 + wc * 64 + ni * 16 + lrow];

#pragma unroll
  for (int mi = 0; mi < 8; ++mi) {
#pragma unroll
    for (int jj = 0; jj < 4; ++jj) {
      const int m = row0 + wr * 128 + mi * 16 + lgrp * 4 + jj;
      const size_t ro = (size_t)m * kD;
      float mk = 1.0f;
      if constexpr (IS_RELA) mk = masks[m];
#pragma unroll
      for (int ni = 0; ni < 4; ++ni) {
        const int col = col0 + wc * 64 + ni * 16 + lrow;
        float v = acc[mi][ni][jj] + biasv[ni];
        v = fmaxf(v, 0.0f) + resid[ro + col];
        if constexpr (IS_RELA) v *= mk;
        out[ro + col] = v;
      }
    }
  }
}

// ---------------------------------------------------------------------------
// Fused launch: blocks 0..1023 = rela GEMM, 1024..1151 = attr GEMM.
// 64 KB LDS + <=128 VGPR -> 2 blocks/CU (the point of this round).
// ---------------------------------------------------------------------------
__global__ __launch_bounds__(512, 4) void gnn_fused(
    const unsigned short* __restrict__ objb,
    const unsigned short* __restrict__ attrb,
    const unsigned short* __restrict__ relab,
    const unsigned short* __restrict__ wab,
    const unsigned short* __restrict__ wrb,
    const int* __restrict__ edges, const float* __restrict__ masks,
    const float* __restrict__ attr, const float* __restrict__ rela,
    const float* __restrict__ b_attr, const float* __restrict__ b_rela,
    float* __restrict__ out1, float* __restrict__ out2) {
  extern __shared__ unsigned short smem[];
  const int bid = blockIdx.x;
  if (bid < 1024) {
    gemm_body<true, 3072, 11, 256>(bid, smem, objb, relab, wrb, edges, masks,
                                   rela, b_rela, out2);
  } else {
    gemm_body<false, 2048, 8, 32>(bid - 1024, smem, objb, attrb, wab, nullptr,
                                  nullptr, attr, b_attr, out1);
  }
}

extern "C" void kernel_launch(void* const* d_in, const int* in_sizes, int n_in,
                              void* d_out, int out_size, void* d_ws,
                              size_t ws_size, hipStream_t stream) {
  (void)in_sizes; (void)n_in; (void)out_size; (void)ws_size;
  const float* obj = (const float*)d_in[0];
  const float* attr = (const float*)d_in[1];
  const float* rela = (const float*)d_in[2];
  const int* edges = (const int*)d_in[3];
  const float* masks = (const float*)d_in[4];
  const float* W_attr = (const float*)d_in[5];
  const float* b_attr = (const float*)d_in[6];
  const float* W_rela = (const float*)d_in[7];
  const float* b_rela = (const float*)d_in[8];

  float* out0 = (float*)d_out;
  float* out1 = out0 + (size_t)kB * kN * kD;
  float* out2 = out1 + (size_t)kB * kN * kD;

  constexpr size_t nObj = (size_t)kB * kN * kD;
  constexpr size_t nRela = (size_t)kB * kR * kD;
  constexpr size_t nWa = (size_t)kD * 2 * kD;

  unsigned short* objb = (unsigned short*)d_ws;
  unsigned short* attrb = objb + nObj;
  unsigned short* relab = attrb + nObj;
  unsigned short* wab = relab + nRela;
  unsigned short* wrb = wab + nWa;

  cvt_all<<<2048, 256, 0, stream>>>(obj, attr, rela, W_attr, W_rela, objb,
                                    attrb, relab, wab, wrb, out0);

  constexpr int kSmem = 65536;  // 2 slots x 32 KB -> 2 blocks/CU
  hipFuncSetAttribute((const void*)gnn_fused,
                      hipFuncAttributeMaxDynamicSharedMemorySize, kSmem);
  gnn_fused<<<1152, 512, kSmem, stream>>>(objb, attrb, relab, wab, wrb, edges,
                                          masks, attr, rela, b_attr, b_rela,
                                          out1, out2);
}

// Round 11
// 613.083 us; speedup vs baseline: 9.3814x; 9.3814x over previous
//
#include <hip/hip_runtime.h>
#include <hip/hip_bf16.h>

constexpr int kB = 32;
constexpr int kN = 256;
constexpr int kR = 2048;
constexpr int kD = 1024;

typedef short bf16x8 __attribute__((ext_vector_type(8)));
typedef float f32x4 __attribute__((ext_vector_type(4)));
typedef unsigned short u16x8 __attribute__((ext_vector_type(8)));

__device__ __forceinline__ unsigned short f2bf(float f) {
  union { __hip_bfloat16 h; unsigned short u; } cv;
  cv.h = __float2bfloat16(f);
  return cv.u;
}

__device__ __forceinline__ void gload_lds16(const void* g, void* l) {
  __builtin_amdgcn_global_load_lds(
      (const __attribute__((address_space(1))) unsigned int*)g,
      (__attribute__((address_space(3))) unsigned int*)l, 16, 0, 0);
}

#define FENCE asm volatile("" ::: "memory")
#define LGKM0 asm volatile("s_waitcnt lgkmcnt(0)" ::: "memory")
#define WAITV(n) asm volatile("s_waitcnt vmcnt(" #n ")" ::: "memory")

// ---------------------------------------------------------------------------
// Fused f32->bf16 pre-pass for all 5 GEMM operands + out0 passthrough copy.
// ---------------------------------------------------------------------------
__global__ void cvt_all(const float* __restrict__ obj,
                        const float* __restrict__ attr,
                        const float* __restrict__ rela,
                        const float* __restrict__ wa,
                        const float* __restrict__ wr,
                        unsigned short* __restrict__ objb,
                        unsigned short* __restrict__ attrb,
                        unsigned short* __restrict__ relab,
                        unsigned short* __restrict__ wab,
                        unsigned short* __restrict__ wrb,
                        float* __restrict__ out0) {
  constexpr long n0 = (long)kB * kN * kD / 8;          // obj
  constexpr long c0 = n0;
  constexpr long c1 = c0 + n0;                          // attr
  constexpr long c2 = c1 + (long)kB * kR * kD / 8;      // rela
  constexpr long c3 = c2 + (long)kD * 2 * kD / 8;       // W_attr
  constexpr long c4 = c3 + (long)kD * 3 * kD / 8;       // W_rela
  const long stride = (long)gridDim.x * blockDim.x;
  for (long i = (long)blockIdx.x * blockDim.x + threadIdx.x; i < c4;
       i += stride) {
    const float* s;
    unsigned short* d;
    long j;
    bool isobj = false;
    if (i < c0)      { s = obj;  d = objb;  j = i; isobj = true; }
    else if (i < c1) { s = attr; d = attrb; j = i - c0; }
    else if (i < c2) { s = rela; d = relab; j = i - c1; }
    else if (i < c3) { s = wa;   d = wab;   j = i - c2; }
    else             { s = wr;   d = wrb;   j = i - c3; }
    const float4 a = reinterpret_cast<const float4*>(s)[2 * j];
    const float4 b = reinterpret_cast<const float4*>(s)[2 * j + 1];
    if (isobj) {  // out0 = obj passthrough, fused with the convert read
      reinterpret_cast<float4*>(out0)[2 * j] = a;
      reinterpret_cast<float4*>(out0)[2 * j + 1] = b;
    }
    u16x8 v;
    v[0] = f2bf(a.x); v[1] = f2bf(a.y); v[2] = f2bf(a.z); v[3] = f2bf(a.w);
    v[4] = f2bf(b.x); v[5] = f2bf(b.y); v[6] = f2bf(b.z); v[7] = f2bf(b.w);
    reinterpret_cast<u16x8*>(d)[j] = v;
  }
}

// ---------------------------------------------------------------------------
// 256x256 bf16 GEMM body — byte-exact R8 structure (best verified: 44%
// MfmaUtil, 0 bank conflicts). BK=64 super-tiles (2 proven BK=32 halves),
// 2-slot LDS double buffer (2 x 64 KB), counted vmcnt(4), one-phase-ahead
// register reads, setprio-wrapped MFMA clusters, 2 barriers per 64 K-units.
// Called in a PERSISTENT loop (R11): entry barrier guards LDS slot reuse
// across panel units.
// C[m,d] = relu(sum_k A[m,k]*W[d,k] + bias[d]) + resid[m,d]  (*mask[m] rela)
// A row = concat of 1024-wide segments:
//   attr: [objb m, attrb m]                 (K=2048, T=32)
//   rela: [objb[subj], relab m, objb[obji]] (K=3072, T=48)
// ---------------------------------------------------------------------------
template <bool IS_RELA, int K_TOT, int LOG_RPB, int NPANEL>
__device__ __forceinline__ void gemm_body(
    int bid, unsigned short* smem,
    const unsigned short* __restrict__ objb,
    const unsigned short* __restrict__ seg1b,
    const unsigned short* __restrict__ Wb,
    const int* __restrict__ edges, const float* __restrict__ masks,
    const float* __restrict__ resid, const float* __restrict__ bias,
    float* __restrict__ out) {
  constexpr int T = K_TOT / 64;  // super-tiles

  // XCD mapping: XCD x owns col panel (x>>1); (x&1) splits row panels.
  // Persistent stride 256 == 0 (mod 8) keeps each XCD on ONE col panel
  // for the whole kernel -> W panel stays L2-hot across units.
  const int x = bid & 7;
  const int col0 = (x >> 1) * 256;
  const int panel = (x & 1) * (NPANEL / 2) + (bid >> 3);
  const int row0 = panel * 256;

  const int tid = threadIdx.x;
  const int w = tid >> 6;   // wave 0..7
  const int l = tid & 63;

  // staging: round r in {0,1} of a half covers LDS rows (w*32 + r*16 + l>>2),
  // granule l&3 (16B); source pre-swizzle g = (l&3) ^ ((l>>3)&3) (rule #21).
  const int sw = (((l & 3) ^ ((l >> 3) & 3)) << 4);  // bytes
  const char* pA0[2];
  const char* pA1[2];
  const char* pA2[2];
  const char* pB[2];
#pragma unroll
  for (int r = 0; r < 2; ++r) {
    const int rl = w * 32 + r * 16 + (l >> 2);
    const int m = row0 + rl;
    if constexpr (IS_RELA) {
      const int b = m >> LOG_RPB;
      const int ri = m & ((1 << LOG_RPB) - 1);
      const int2 e =
          *reinterpret_cast<const int2*>(&edges[((size_t)b * kR + ri) * 2]);
      pA0[r] = (const char*)(objb + (size_t)(b * kN + e.x) * kD);
      pA1[r] = (const char*)(seg1b + (size_t)m * kD);
      pA2[r] = (const char*)(objb + (size_t)(b * kN + e.y) * kD);
    } else {
      pA0[r] = (const char*)(objb + (size_t)m * kD);
      pA1[r] = (const char*)(seg1b + (size_t)m * kD);
      pA2[r] = pA0[r];
    }
    pB[r] = (const char*)(Wb + (size_t)(col0 + rl) * K_TOT);
  }

  const int wr = w >> 2;
  const int wc = w & 3;
  const int lrow = l & 15;
  const int lgrp = l >> 4;
  const int pgr = ((lgrp ^ ((lrow >> 1) & 3)) << 3);  // shorts

  f32x4 acc[8][4] = {};
  bf16x8 AfX[4], AfY[4], Bf0[4], Bf1[4];

  // slot layout (shorts): S*32768 + { Ah0:0, Ah1:8192, Bh0:16384, Bh1:24576 }
  auto issueA = [&](int tn, int h, int slot) {
    unsigned short* ra = smem + slot * 32768 + h * 8192;
    const int kb = tn * 64 + h * 32;           // wave-uniform bf16 k-base
    const int seg = kb >> 10;
    const uint32_t ko = (uint32_t)(kb & 1023) * 2;
#pragma unroll
    for (int r = 0; r < 2; ++r) {
      const char* srcA;
      if constexpr (IS_RELA) {
        srcA = (seg == 1) ? pA1[r] : ((seg == 0) ? pA0[r] : pA2[r]);
      } else {
        srcA = (seg == 0) ? pA0[r] : pA1[r];
      }
      gload_lds16(srcA + ko + sw, ra + (w * 2 + r) * 512);
    }
  };
  auto issueB = [&](int tn, int h, int slot) {
    unsigned short* rb = smem + slot * 32768 + 16384 + h * 8192;
    const uint32_t kb2 = (uint32_t)(tn * 64 + h * 32) * 2;
#pragma unroll
    for (int r = 0; r < 2; ++r)
      gload_lds16(pB[r] + kb2 + sw, rb + (w * 2 + r) * 512);
  };

#define RD_A4(SET, SLOT, KK, MOFF)                                         \
  _Pragma("unroll")                                                        \
  for (int mi = 0; mi < 4; ++mi)                                           \
    SET[mi] = *reinterpret_cast<const bf16x8*>(                            \
        &smem[(SLOT) * 32768 + (KK) * 8192 +                               \
              (wr * 128 + ((MOFF) + mi) * 16 + lrow) * 32 + pgr]);

#define RD_B4(SET, SLOT, KK)                                               \
  _Pragma("unroll")                                                        \
  for (int ni = 0; ni < 4; ++ni)                                           \
    SET[ni] = *reinterpret_cast<const bf16x8*>(                            \
        &smem[(SLOT) * 32768 + 16384 + (KK) * 8192 +                       \
              (wc * 64 + ni * 16 + lrow) * 32 + pgr]);

#define MFMA16(MOFF, ASET, BSET)                                           \
  __builtin_amdgcn_s_setprio(1);                                           \
  _Pragma("unroll")                                                        \
  for (int mi = 0; mi < 4; ++mi)                                           \
    _Pragma("unroll")                                                      \
    for (int ni = 0; ni < 4; ++ni)                                         \
      acc[(MOFF) + mi][ni] = __builtin_amdgcn_mfma_f32_16x16x32_bf16(      \
          ASET[mi], BSET[ni], acc[(MOFF) + mi][ni], 0, 0, 0);              \
  __builtin_amdgcn_s_setprio(0);

// Super-tile t in slot S (compile-time 0/1); issues tile t+1 into S^1.
#define STILE(t, S)                                                        \
  {                                                                        \
    /* sp0 */                                                              \
    issueA((t) + 1, 0, (S) ^ 1);                                           \
    RD_A4(AfY, S, 0, 4);                                                   \
    MFMA16(0, AfX, Bf0);                                                   \
    /* sp1 */                                                              \
    issueB((t) + 1, 0, (S) ^ 1);                                           \
    WAITV(4);                                                              \
    __builtin_amdgcn_s_barrier();                                          \
    FENCE;                                                                 \
    RD_A4(AfX, S, 1, 0);                                                   \
    RD_B4(Bf1, S, 1);                                                      \
    MFMA16(4, AfY, Bf0);                                                   \
    /* sp2 */                                                              \
    issueA((t) + 1, 1, (S) ^ 1);                                           \
    RD_A4(AfY, S, 1, 4);                                                   \
    MFMA16(0, AfX, Bf1);                                                   \
    /* sp3 */                                                              \
    issueB((t) + 1, 1, (S) ^ 1);                                           \
    WAITV(4);                                                              \
    __builtin_amdgcn_s_barrier();                                          \
    FENCE;                                                                 \
    RD_A4(AfX, (S) ^ 1, 0, 0);                                             \
    RD_B4(Bf0, (S) ^ 1, 0);                                                \
    MFMA16(4, AfY, Bf1);                                                   \
  }

  // entry barrier: guards LDS slot reuse across persistent panel units
  __builtin_amdgcn_s_barrier();
  FENCE;

  // prologue: tile 0's four halves in steady-state order; half-0 resident.
  issueA(0, 0, 0); issueB(0, 0, 0);
  issueA(0, 1, 0); issueB(0, 1, 0);
  WAITV(4);  // Ah0,Bh0(0) landed; Ah1,Bh1(0) in flight
  __builtin_amdgcn_s_barrier();
  FENCE;
  RD_A4(AfX, 0, 0, 0);
  RD_B4(Bf0, 0, 0);

  // main loop: super-tiles 0 .. T-2 (T even: 48 rela / 32 attr)
#pragma unroll 1
  for (int it = 0; it < (T - 2) / 2; ++it) {
    STILE(2 * it, 0);
    STILE(2 * it + 1, 1);
  }
  STILE(T - 2, 0);  // issues tile T-1 into slot 1

  // tail: super-tile T-1 in slot 1, no issues.
  {
    RD_A4(AfY, 1, 0, 4);            // sp0
    MFMA16(0, AfX, Bf0);
    WAITV(0);                       // sp1: drain Ah1,Bh1(T-1)
    __builtin_amdgcn_s_barrier();
    FENCE;
    RD_A4(AfX, 1, 1, 0);
    RD_B4(Bf1, 1, 1);
    MFMA16(4, AfY, Bf0);
    RD_A4(AfY, 1, 1, 4);            // sp2
    MFMA16(0, AfX, Bf1);
    MFMA16(4, AfY, Bf1);            // sp3
  }

#undef STILE
#undef MFMA16
#undef RD_B4
#undef RD_A4

  // epilogue: bias + relu + residual (+mask)
  float biasv[4];
#pragma unroll
  for (int ni = 0; ni < 4; ++ni)
    biasv[ni] = bias[col0 + wc * 64 + ni * 16 + lrow];

#pragma unroll
  for (int mi = 0; mi < 8; ++mi) {
#pragma unroll
    for (int jj = 0; jj < 4; ++jj) {
      const int m = row0 + wr * 128 + mi * 16 + lgrp * 4 + jj;
      const size_t ro = (size_t)m * kD;
      float mk = 1.0f;
      if constexpr (IS_RELA) mk = masks[m];
#pragma unroll
      for (int ni = 0; ni < 4; ++ni) {
        const int col = col0 + wc * 64 + ni * 16 + lrow;
        float v = acc[mi][ni][jj] + biasv[ni];
        v = fmaxf(v, 0.0f) + resid[ro + col];
        if constexpr (IS_RELA) v *= mk;
        out[ro + col] = v;
      }
    }
  }
}

// ---------------------------------------------------------------------------
// PERSISTENT fused launch: 256 blocks (1/CU); each block loops over units
// u = bid, bid+256, ... (1152 total: 0..1023 rela, 1024..1151 attr).
// u % 8 == bid % 8, so each XCD keeps its B col-panel L2-hot all kernel.
// ---------------------------------------------------------------------------
__global__ __launch_bounds__(512, 2) void gnn_fused(
    const unsigned short* __restrict__ objb,
    const unsigned short* __restrict__ attrb,
    const unsigned short* __restrict__ relab,
    const unsigned short* __restrict__ wab,
    const unsigned short* __restrict__ wrb,
    const int* __restrict__ edges, const float* __restrict__ masks,
    const float* __restrict__ attr, const float* __restrict__ rela,
    const float* __restrict__ b_attr, const float* __restrict__ b_rela,
    float* __restrict__ out1, float* __restrict__ out2) {
  extern __shared__ unsigned short smem[];
#pragma unroll 1
  for (int u = blockIdx.x; u < 1152; u += 256) {
    if (u < 1024) {
      gemm_body<true, 3072, 11, 256>(u, smem, objb, relab, wrb, edges, masks,
                                     rela, b_rela, out2);
    } else {
      gemm_body<false, 2048, 8, 32>(u - 1024, smem, objb, attrb, wab, nullptr,
                                    nullptr, attr, b_attr, out1);
    }
  }
}

extern "C" void kernel_launch(void* const* d_in, const int* in_sizes, int n_in,
                              void* d_out, int out_size, void* d_ws,
                              size_t ws_size, hipStream_t stream) {
  (void)in_sizes; (void)n_in; (void)out_size; (void)ws_size;
  const float* obj = (const float*)d_in[0];
  const float* attr = (const float*)d_in[1];
  const float* rela = (const float*)d_in[2];
  const int* edges = (const int*)d_in[3];
  const float* masks = (const float*)d_in[4];
  const float* W_attr = (const float*)d_in[5];
  const float* b_attr = (const float*)d_in[6];
  const float* W_rela = (const float*)d_in[7];
  const float* b_rela = (const float*)d_in[8];

  float* out0 = (float*)d_out;
  float* out1 = out0 + (size_t)kB * kN * kD;
  float* out2 = out1 + (size_t)kB * kN * kD;

  constexpr size_t nObj = (size_t)kB * kN * kD;
  constexpr size_t nRela = (size_t)kB * kR * kD;
  constexpr size_t nWa = (size_t)kD * 2 * kD;

  unsigned short* objb = (unsigned short*)d_ws;
  unsigned short* attrb = objb + nObj;
  unsigned short* relab = attrb + nObj;
  unsigned short* wab = relab + nRela;
  unsigned short* wrb = wab + nWa;

  cvt_all<<<2048, 256, 0, stream>>>(obj, attr, rela, W_attr, W_rela, objb,
                                    attrb, relab, wab, wrb, out0);

  constexpr int kSmem = 131072;
  hipFuncSetAttribute((const void*)gnn_fused,
                      hipFuncAttributeMaxDynamicSharedMemorySize, kSmem);
  gnn_fused<<<256, 512, kSmem, stream>>>(objb, attrb, relab, wab, wrb, edges,
                                         masks, attr, rela, b_attr, b_rela,
                                         out1, out2);
}